// Round 11
// baseline (823.090 us; speedup 1.0000x reference)
//
#include <hip/hip_runtime.h>

#define NHID 48
#define BN_EPS 1e-5f
#define SLOPE 0.01f
#define DMAX 64

typedef short short8 __attribute__((ext_vector_type(8)));
typedef float f32x4 __attribute__((ext_vector_type(4)));

// ---------- bf16 helpers (fp32 compute, bf16 storage, RNE pack) ----------
__device__ __forceinline__ float bf_lo(unsigned u) { union { unsigned i; float f; } c; c.i = u << 16; return c.f; }
__device__ __forceinline__ float bf_hi(unsigned u) { union { unsigned i; float f; } c; c.i = u & 0xffff0000u; return c.f; }
__device__ __forceinline__ unsigned bf_rne(float x) { union { float f; unsigned i; } c; c.f = x; return (c.i + 0x7fffu + ((c.i >> 16) & 1u)) >> 16; }
__device__ __forceinline__ unsigned packbf(float lo, float hi) { return bf_rne(lo) | (bf_rne(hi) << 16); }

__device__ __forceinline__ void acc8(float (&a)[8], float w, const uint4& v) {
    a[0] = fmaf(w, bf_lo(v.x), a[0]); a[1] = fmaf(w, bf_hi(v.x), a[1]);
    a[2] = fmaf(w, bf_lo(v.y), a[2]); a[3] = fmaf(w, bf_hi(v.y), a[3]);
    a[4] = fmaf(w, bf_lo(v.z), a[4]); a[5] = fmaf(w, bf_hi(v.z), a[5]);
    a[6] = fmaf(w, bf_lo(v.w), a[6]); a[7] = fmaf(w, bf_hi(v.w), a[7]);
}

// ---------- setup: out-degree + padded-CSR scatter (grid-stride) ----------
__global__ void k_setup(const int* __restrict__ src, const int* __restrict__ dst,
                        float* __restrict__ degf, int* __restrict__ cur,
                        int* __restrict__ csrc, int nE) {
    for (int e = blockIdx.x * blockDim.x + threadIdx.x; e < nE; e += gridDim.x * blockDim.x) {
        int s = src[e], d = dst[e];
        atomicAdd(&degf[s], 1.0f);
        int r = atomicAdd(&cur[d], 1);
        if (r < DMAX) csrc[(size_t)d * DMAX + r] = s;
    }
}

// ---------- dinv + input cast (row-major bf16), fused ----------
__global__ void k_dinvcast(float* __restrict__ deg, int nN,
                           const float4* __restrict__ xin, uint2* __restrict__ outv, int n4) {
    int stride = gridDim.x * blockDim.x;
    int gid = blockIdx.x * blockDim.x + threadIdx.x;
    for (int i = gid; i < n4; i += stride) {
        float4 v = xin[i];
        outv[i] = make_uint2(packbf(v.x, v.y), packbf(v.z, v.w));
    }
    for (int i = gid; i < nN; i += stride) {
        float d = deg[i];
        deg[i] = (d > 0.f) ? rsqrtf(d) : 0.f;
    }
}

// ---------- propagation: one wave per node, 32 edges in flight, grid-stride ----------
// lane: x = lane&7 (uint4 chunk), y = lane>>3 (edge slot)
template <int NV>
__global__ void k_prop(const uint4* __restrict__ Tin, const uint4* __restrict__ Tprev,
                       uint4* __restrict__ Tout, const int* __restrict__ cnt,
                       const int* __restrict__ csrc, const float* __restrict__ dinv,
                       int nN, int mode) {
    const int lane = threadIdx.x;
    const int x = lane & 7;
    const int y = lane >> 3;
    const int nw = blockDim.y;
    for (int n = blockIdx.x * nw + threadIdx.y; n < nN; n += gridDim.x * nw) {
        int eb = n << 6;
        int c = cnt[n]; if (c > DMAX) c = DMAX;
        float a[8] = {0.f, 0.f, 0.f, 0.f, 0.f, 0.f, 0.f, 0.f};
        for (int it = 0; it < c; it += 32) {
            int j0 = it + y, j1 = it + 8 + y, j2 = it + 16 + y, j3 = it + 24 + y;
            int s0 = (j0 < c) ? csrc[eb + j0] : 0;
            int s1 = (j1 < c) ? csrc[eb + j1] : 0;
            int s2 = (j2 < c) ? csrc[eb + j2] : 0;
            int s3 = (j3 < c) ? csrc[eb + j3] : 0;
            float w0 = (j0 < c) ? dinv[s0] : 0.f;
            float w1 = (j1 < c) ? dinv[s1] : 0.f;
            float w2 = (j2 < c) ? dinv[s2] : 0.f;
            float w3 = (j3 < c) ? dinv[s3] : 0.f;
            if (x < NV) {
                uint4 q0 = Tin[(size_t)s0 * NV + x];
                uint4 q1 = Tin[(size_t)s1 * NV + x];
                uint4 q2 = Tin[(size_t)s2 * NV + x];
                uint4 q3 = Tin[(size_t)s3 * NV + x];
                acc8(a, w0, q0);
                acc8(a, w1, q1);
                acc8(a, w2, q2);
                acc8(a, w3, q3);
            }
        }
#pragma unroll
        for (int k = 0; k < 8; ++k) {
            float v = a[k];
            v += __shfl_xor(v, 8);
            v += __shfl_xor(v, 16);
            v += __shfl_xor(v, 32);
            a[k] = v;
        }
        if (y == 0 && x < NV) {
            float dn = -dinv[n];
            size_t o = (size_t)n * NV + x;
            uint4 r;
            if (mode) {
                uint4 p = Tprev[o];
                float t = 2.f * dn;
                r.x = packbf(fmaf(t, a[0], -bf_lo(p.x)), fmaf(t, a[1], -bf_hi(p.x)));
                r.y = packbf(fmaf(t, a[2], -bf_lo(p.y)), fmaf(t, a[3], -bf_hi(p.y)));
                r.z = packbf(fmaf(t, a[4], -bf_lo(p.z)), fmaf(t, a[5], -bf_hi(p.z)));
                r.w = packbf(fmaf(t, a[6], -bf_lo(p.w)), fmaf(t, a[7], -bf_hi(p.w)));
            } else {
                r.x = packbf(dn * a[0], dn * a[1]);
                r.y = packbf(dn * a[2], dn * a[3]);
                r.z = packbf(dn * a[4], dn * a[5]);
                r.w = packbf(dn * a[6], dn * a[7]);
            }
            Tout[o] = r;
        }
    }
}

// ---------- MFMA matmul over 5 Chebyshev terms ----------
// Tslab: [5][nN][WIN] bf16 contiguous; W: [K=5*WIN][48] fp32 (k = t*WIN+f matches)
// MODE 0: Hout(bf16) = bias + slab@W; BN sums epilogue -> bns
// MODE 1: out(f32)   = (bias + slab@W) @ Wf + bf
template <int WIN, int MODE>
__global__ __launch_bounds__(256) void k_mmf(
    const unsigned short* __restrict__ Tslab, const float* __restrict__ Wb,
    const float* __restrict__ bias, unsigned short* __restrict__ Hout,
    float* __restrict__ bns, const float* __restrict__ Wf,
    const float* __restrict__ bfin, float* __restrict__ out, int nN) {
    constexpr int K = 5 * WIN;
    constexpr int NC = (K + 31) / 32;
    const int lane = threadIdx.x & 63;
    const int wid = threadIdx.x >> 6;
    const int col = lane & 15;
    const int sub = lane >> 4;
    const size_t termStride = (size_t)nN * WIN;

    short8 bfrag[3][NC];
#pragma unroll
    for (int ct = 0; ct < 3; ++ct) {
        int j = ct * 16 + col;
#pragma unroll
        for (int c = 0; c < NC; ++c) {
            short8 b;
#pragma unroll
            for (int r = 0; r < 8; ++r) {
                int k = c * 32 + sub * 8 + r;
                float w = (k < K) ? Wb[(size_t)k * 48 + j] : 0.f;
                b[r] = (short)bf_rne(w);
            }
            bfrag[ct][c] = b;
        }
    }
    float bj0 = bias[col], bj1 = bias[16 + col], bj2 = bias[32 + col];
    float wf00 = 0.f, wf01 = 0.f, wf02 = 0.f, wf10 = 0.f, wf11 = 0.f, wf12 = 0.f;
    float bf0 = 0.f, bf1 = 0.f;
    if (MODE == 1) {
        wf00 = Wf[(col) * 2 + 0];      wf10 = Wf[(col) * 2 + 1];
        wf01 = Wf[(16 + col) * 2 + 0]; wf11 = Wf[(16 + col) * 2 + 1];
        wf02 = Wf[(32 + col) * 2 + 0]; wf12 = Wf[(32 + col) * 2 + 1];
        bf0 = bfin[0]; bf1 = bfin[1];
    }
    float s0 = 0.f, s1 = 0.f, s2 = 0.f, q0 = 0.f, q1 = 0.f, q2 = 0.f;

    const int ntiles = (nN + 15) >> 4;
    for (int tile = blockIdx.x * 4 + wid; tile < ntiles; tile += gridDim.x * 4) {
        int n0 = tile << 4;
        int arow = n0 + col;
        bool rowok = arow < nN;
        f32x4 acc0 = {0.f, 0.f, 0.f, 0.f};
        f32x4 acc1 = {0.f, 0.f, 0.f, 0.f};
        f32x4 acc2 = {0.f, 0.f, 0.f, 0.f};
#pragma unroll
        for (int c = 0; c < NC; ++c) {
            int k = c * 32 + sub * 8;
            short8 a = {};
            if (rowok && k < K) {
                int t = k / WIN, f = k % WIN;
                a = *(const short8*)(Tslab + (size_t)t * termStride + (size_t)arow * WIN + f);
            }
            acc0 = __builtin_amdgcn_mfma_f32_16x16x32_bf16(a, bfrag[0][c], acc0, 0, 0, 0);
            acc1 = __builtin_amdgcn_mfma_f32_16x16x32_bf16(a, bfrag[1][c], acc1, 0, 0, 0);
            acc2 = __builtin_amdgcn_mfma_f32_16x16x32_bf16(a, bfrag[2][c], acc2, 0, 0, 0);
        }
        int nb = n0 + sub * 4;
        if (MODE == 0) {
#pragma unroll
            for (int r = 0; r < 4; ++r) {
                int n = nb + r;
                if (n < nN) {
                    float v0 = acc0[r] + bj0;
                    float v1 = acc1[r] + bj1;
                    float v2 = acc2[r] + bj2;
                    size_t ro = (size_t)n * NHID;
                    Hout[ro + col]      = (unsigned short)bf_rne(v0);
                    Hout[ro + 16 + col] = (unsigned short)bf_rne(v1);
                    Hout[ro + 32 + col] = (unsigned short)bf_rne(v2);
                    s0 += v0; q0 += v0 * v0;
                    s1 += v1; q1 += v1 * v1;
                    s2 += v2; q2 += v2 * v2;
                }
            }
        } else {
#pragma unroll
            for (int r = 0; r < 4; ++r) {
                float p0 = fmaf(acc0[r] + bj0, wf00, fmaf(acc1[r] + bj1, wf01, (acc2[r] + bj2) * wf02));
                float p1 = fmaf(acc0[r] + bj0, wf10, fmaf(acc1[r] + bj1, wf11, (acc2[r] + bj2) * wf12));
                p0 += __shfl_xor(p0, 1); p0 += __shfl_xor(p0, 2);
                p0 += __shfl_xor(p0, 4); p0 += __shfl_xor(p0, 8);
                p1 += __shfl_xor(p1, 1); p1 += __shfl_xor(p1, 2);
                p1 += __shfl_xor(p1, 4); p1 += __shfl_xor(p1, 8);
                int n = nb + r;
                if (col == 0 && n < nN) {
                    out[(size_t)n * 2 + 0] = p0 + bf0;
                    out[(size_t)n * 2 + 1] = p1 + bf1;
                }
            }
        }
    }
    if (MODE == 0) {
        s0 += __shfl_xor(s0, 16); s0 += __shfl_xor(s0, 32);
        s1 += __shfl_xor(s1, 16); s1 += __shfl_xor(s1, 32);
        s2 += __shfl_xor(s2, 16); s2 += __shfl_xor(s2, 32);
        q0 += __shfl_xor(q0, 16); q0 += __shfl_xor(q0, 32);
        q1 += __shfl_xor(q1, 16); q1 += __shfl_xor(q1, 32);
        q2 += __shfl_xor(q2, 16); q2 += __shfl_xor(q2, 32);
        __shared__ float red[4][96];
        if (lane < 16) {
            red[wid][col]      = s0; red[wid][16 + col] = s1; red[wid][32 + col] = s2;
            red[wid][48 + col] = q0; red[wid][64 + col] = q1; red[wid][80 + col] = q2;
        }
        __syncthreads();
        int t = threadIdx.x;
        if (t < 96) atomicAdd(&bns[t], red[0][t] + red[1][t] + red[2][t] + red[3][t]);
    }
}

// ---------- batchnorm apply + LeakyReLU (grid-stride) ----------
__global__ void k_bn_apply(const unsigned short* __restrict__ Hin, unsigned short* __restrict__ T0,
                           const float* __restrict__ sums, const float* __restrict__ g,
                           const float* __restrict__ b, int nN) {
    int col = threadIdx.x;
    float inv = 1.f / (float)nN;
    float mu = sums[col] * inv;
    float var = sums[NHID + col] * inv - mu * mu;
    float rs = rsqrtf(var + BN_EPS) * g[col];
    float bb = b[col];
    for (int n = blockIdx.x * 8 + threadIdx.y; n < nN; n += gridDim.x * 8) {
        size_t o = (size_t)n * NHID + col;
        float y = (bf_lo(Hin[o]) - mu) * rs + bb;
        y = (y >= 0.f) ? y : SLOPE * y;
        T0[o] = (unsigned short)bf_rne(y);
    }
}

extern "C" void kernel_launch(void* const* d_in, const int* in_sizes, int n_in,
                              void* d_out, int out_size, void* d_ws, size_t ws_size,
                              hipStream_t stream) {
    const float* x   = (const float*)d_in[0];
    const int*   ei  = (const int*)d_in[1];
    const float* W1  = (const float*)d_in[2];
    const float* b1  = (const float*)d_in[3];
    const float* W2  = (const float*)d_in[4];
    const float* b2  = (const float*)d_in[5];
    const float* W3  = (const float*)d_in[6];
    const float* b3  = (const float*)d_in[7];
    const float* g1  = (const float*)d_in[8];
    const float* bt1 = (const float*)d_in[9];
    const float* g2  = (const float*)d_in[10];
    const float* bt2 = (const float*)d_in[11];
    const float* Wf  = (const float*)d_in[12];
    const float* bf  = (const float*)d_in[13];
    float* out = (float*)d_out;

    const int nN = in_sizes[0] / 64;
    const int nE = in_sizes[1] / 2;
    const int* src = ei;
    const int* dst = ei + nE;

    size_t off = 0;
    auto carve = [&](size_t bytes) -> void* {
        void* p = (char*)d_ws + off;
        off += (bytes + 255) & ~(size_t)255;
        return p;
    };
    float*          dinv = (float*)carve((size_t)nN * 4);
    int*            cur  = (int*)carve((size_t)nN * 4);
    int*            csrc = (int*)carve((size_t)nN * DMAX * 4);
    unsigned short* slab = (unsigned short*)carve((size_t)nN * 64 * 2 * 5);  // [5][nN][64]; 48-slab aliases
    unsigned short* H    = (unsigned short*)carve((size_t)nN * NHID * 2);
    float*          bns  = (float*)carve(2 * NHID * 4);

    const size_t ts64 = (size_t)nN * 64;
    const size_t ts48 = (size_t)nN * NHID;

    // dinv and cur are adjacent carves (256-aligned) -> one memset covers both
    hipMemsetAsync(dinv, 0, (size_t)((char*)csrc - (char*)dinv), stream);

    k_setup<<<4096, 256, 0, stream>>>(src, dst, dinv, cur, csrc, nE);
    k_dinvcast<<<2048, 256, 0, stream>>>(dinv, nN, (const float4*)x, (uint2*)slab, nN * 16);

    const int gP = 1024;             // 8192 resident waves: 1024 blocks x 8 waves
    const dim3 blkP(64, 8);
    const int gM = 1024;

    auto prop = [&](const unsigned short* Tin, const unsigned short* Tprev,
                    unsigned short* Tout, int NVw, int mode) {
        if (NVw == 8)
            k_prop<8><<<gP, blkP, 0, stream>>>((const uint4*)Tin, (const uint4*)(Tprev ? Tprev : Tin),
                                               (uint4*)Tout, cur, csrc, dinv, nN, mode);
        else
            k_prop<6><<<gP, blkP, 0, stream>>>((const uint4*)Tin, (const uint4*)(Tprev ? Tprev : Tin),
                                               (uint4*)Tout, cur, csrc, dinv, nN, mode);
    };

    // ---- layer 1 (Win=64) ----
    unsigned short* L1[5];
    for (int t = 0; t < 5; ++t) L1[t] = slab + t * ts64;
    prop(L1[0], nullptr, L1[1], 8, 0);
    prop(L1[1], L1[0], L1[2], 8, 1);
    prop(L1[2], L1[1], L1[3], 8, 1);
    prop(L1[3], L1[2], L1[4], 8, 1);
    hipMemsetAsync(bns, 0, 2 * NHID * 4, stream);
    k_mmf<64, 0><<<gM, 256, 0, stream>>>(slab, W1, b1, H, bns, nullptr, nullptr, nullptr, nN);
    k_bn_apply<<<2048, dim3(NHID, 8), 0, stream>>>(H, slab, bns, g1, bt1, nN);

    // ---- layer 2 (Win=48) ----
    unsigned short* L2[5];
    for (int t = 0; t < 5; ++t) L2[t] = slab + t * ts48;
    prop(L2[0], nullptr, L2[1], 6, 0);
    prop(L2[1], L2[0], L2[2], 6, 1);
    prop(L2[2], L2[1], L2[3], 6, 1);
    prop(L2[3], L2[2], L2[4], 6, 1);
    hipMemsetAsync(bns, 0, 2 * NHID * 4, stream);
    k_mmf<48, 0><<<gM, 256, 0, stream>>>(slab, W2, b2, H, bns, nullptr, nullptr, nullptr, nN);
    k_bn_apply<<<2048, dim3(NHID, 8), 0, stream>>>(H, slab, bns, g2, bt2, nN);

    // ---- layer 3 (Win=48) + fused final linear ----
    prop(L2[0], nullptr, L2[1], 6, 0);
    prop(L2[1], L2[0], L2[2], 6, 1);
    prop(L2[2], L2[1], L2[3], 6, 1);
    prop(L2[3], L2[2], L2[4], 6, 1);
    k_mmf<48, 1><<<gM, 256, 0, stream>>>(slab, W3, b3, nullptr, nullptr, Wf, bf, out, nN);
}

// Round 12
// 789.476 us; speedup vs baseline: 1.0426x; 1.0426x over previous
//
#include <hip/hip_runtime.h>

#define NHID 48
#define BN_EPS 1e-5f
#define SLOPE 0.01f
#define DMAX 64

typedef short short8 __attribute__((ext_vector_type(8)));
typedef float f32x4 __attribute__((ext_vector_type(4)));

// ---------- bf16 helpers (fp32 compute, bf16 storage, RNE pack) ----------
__device__ __forceinline__ float bf_lo(unsigned u) { union { unsigned i; float f; } c; c.i = u << 16; return c.f; }
__device__ __forceinline__ float bf_hi(unsigned u) { union { unsigned i; float f; } c; c.i = u & 0xffff0000u; return c.f; }
__device__ __forceinline__ unsigned bf_rne(float x) { union { float f; unsigned i; } c; c.f = x; return (c.i + 0x7fffu + ((c.i >> 16) & 1u)) >> 16; }
__device__ __forceinline__ unsigned packbf(float lo, float hi) { return bf_rne(lo) | (bf_rne(hi) << 16); }

__device__ __forceinline__ void acc8(float (&a)[8], float w, const uint4& v) {
    a[0] = fmaf(w, bf_lo(v.x), a[0]); a[1] = fmaf(w, bf_hi(v.x), a[1]);
    a[2] = fmaf(w, bf_lo(v.y), a[2]); a[3] = fmaf(w, bf_hi(v.y), a[3]);
    a[4] = fmaf(w, bf_lo(v.z), a[4]); a[5] = fmaf(w, bf_hi(v.z), a[5]);
    a[6] = fmaf(w, bf_lo(v.w), a[6]); a[7] = fmaf(w, bf_hi(v.w), a[7]);
}

// ---------- setup: out-degree + padded-CSR scatter (grid-stride) ----------
__global__ void k_setup(const int* __restrict__ src, const int* __restrict__ dst,
                        float* __restrict__ degf, int* __restrict__ cur,
                        int* __restrict__ csrc, int nE) {
    for (int e = blockIdx.x * blockDim.x + threadIdx.x; e < nE; e += gridDim.x * blockDim.x) {
        int s = src[e], d = dst[e];
        atomicAdd(&degf[s], 1.0f);
        int r = atomicAdd(&cur[d], 1);
        if (r < DMAX) csrc[(size_t)d * DMAX + r] = s;
    }
}

// ---------- dinv + input cast (row-major bf16), fused ----------
__global__ void k_dinvcast(float* __restrict__ deg, int nN,
                           const float4* __restrict__ xin, uint2* __restrict__ outv, int n4) {
    int stride = gridDim.x * blockDim.x;
    int gid = blockIdx.x * blockDim.x + threadIdx.x;
    for (int i = gid; i < n4; i += stride) {
        float4 v = xin[i];
        outv[i] = make_uint2(packbf(v.x, v.y), packbf(v.z, v.w));
    }
    for (int i = gid; i < nN; i += stride) {
        float d = deg[i];
        deg[i] = (d > 0.f) ? rsqrtf(d) : 0.f;
    }
}

// ---------- propagation: one wave per node, 32 edges in flight, grid-stride ----------
// lane: x = lane&7 (uint4 chunk), y = lane>>3 (edge slot)
template <int NV>
__global__ void k_prop(const uint4* __restrict__ Tin, const uint4* __restrict__ Tprev,
                       uint4* __restrict__ Tout, const int* __restrict__ cnt,
                       const int* __restrict__ csrc, const float* __restrict__ dinv,
                       int nN, int mode) {
    const int lane = threadIdx.x;
    const int x = lane & 7;
    const int y = lane >> 3;
    for (int n = blockIdx.x * 4 + threadIdx.y; n < nN; n += gridDim.x * 4) {
        int eb = n << 6;
        int c = cnt[n]; if (c > DMAX) c = DMAX;
        float a[8] = {0.f, 0.f, 0.f, 0.f, 0.f, 0.f, 0.f, 0.f};
        for (int it = 0; it < c; it += 32) {
            int j0 = it + y, j1 = it + 8 + y, j2 = it + 16 + y, j3 = it + 24 + y;
            int s0 = (j0 < c) ? csrc[eb + j0] : 0;
            int s1 = (j1 < c) ? csrc[eb + j1] : 0;
            int s2 = (j2 < c) ? csrc[eb + j2] : 0;
            int s3 = (j3 < c) ? csrc[eb + j3] : 0;
            float w0 = (j0 < c) ? dinv[s0] : 0.f;
            float w1 = (j1 < c) ? dinv[s1] : 0.f;
            float w2 = (j2 < c) ? dinv[s2] : 0.f;
            float w3 = (j3 < c) ? dinv[s3] : 0.f;
            if (x < NV) {
                uint4 q0 = Tin[(size_t)s0 * NV + x];
                uint4 q1 = Tin[(size_t)s1 * NV + x];
                uint4 q2 = Tin[(size_t)s2 * NV + x];
                uint4 q3 = Tin[(size_t)s3 * NV + x];
                acc8(a, w0, q0);
                acc8(a, w1, q1);
                acc8(a, w2, q2);
                acc8(a, w3, q3);
            }
        }
#pragma unroll
        for (int k = 0; k < 8; ++k) {
            float v = a[k];
            v += __shfl_xor(v, 8);
            v += __shfl_xor(v, 16);
            v += __shfl_xor(v, 32);
            a[k] = v;
        }
        if (y == 0 && x < NV) {
            float dn = -dinv[n];
            size_t o = (size_t)n * NV + x;
            uint4 r;
            if (mode) {
                uint4 p = Tprev[o];
                float t = 2.f * dn;
                r.x = packbf(fmaf(t, a[0], -bf_lo(p.x)), fmaf(t, a[1], -bf_hi(p.x)));
                r.y = packbf(fmaf(t, a[2], -bf_lo(p.y)), fmaf(t, a[3], -bf_hi(p.y)));
                r.z = packbf(fmaf(t, a[4], -bf_lo(p.z)), fmaf(t, a[5], -bf_hi(p.z)));
                r.w = packbf(fmaf(t, a[6], -bf_lo(p.w)), fmaf(t, a[7], -bf_hi(p.w)));
            } else {
                r.x = packbf(dn * a[0], dn * a[1]);
                r.y = packbf(dn * a[2], dn * a[3]);
                r.z = packbf(dn * a[4], dn * a[5]);
                r.w = packbf(dn * a[6], dn * a[7]);
            }
            Tout[o] = r;
        }
    }
}

// ---------- MFMA matmul over 5 Chebyshev terms ----------
// Tslab: [5][nN][WIN] bf16 contiguous; W: [K=5*WIN][48] fp32 (k = t*WIN+f matches)
// MODE 0: Hout(bf16) = bias + slab@W; BN sums epilogue -> bns
// MODE 1: out(f32)   = (bias + slab@W) @ Wf + bf
template <int WIN, int MODE>
__global__ __launch_bounds__(256) void k_mmf(
    const unsigned short* __restrict__ Tslab, const float* __restrict__ Wb,
    const float* __restrict__ bias, unsigned short* __restrict__ Hout,
    float* __restrict__ bns, const float* __restrict__ Wf,
    const float* __restrict__ bfin, float* __restrict__ out, int nN) {
    constexpr int K = 5 * WIN;
    constexpr int NC = (K + 31) / 32;
    const int lane = threadIdx.x & 63;
    const int wid = threadIdx.x >> 6;
    const int col = lane & 15;
    const int sub = lane >> 4;
    const size_t termStride = (size_t)nN * WIN;

    short8 bfrag[3][NC];
#pragma unroll
    for (int ct = 0; ct < 3; ++ct) {
        int j = ct * 16 + col;
#pragma unroll
        for (int c = 0; c < NC; ++c) {
            short8 b;
#pragma unroll
            for (int r = 0; r < 8; ++r) {
                int k = c * 32 + sub * 8 + r;
                float w = (k < K) ? Wb[(size_t)k * 48 + j] : 0.f;
                b[r] = (short)bf_rne(w);
            }
            bfrag[ct][c] = b;
        }
    }
    float bj0 = bias[col], bj1 = bias[16 + col], bj2 = bias[32 + col];
    float wf00 = 0.f, wf01 = 0.f, wf02 = 0.f, wf10 = 0.f, wf11 = 0.f, wf12 = 0.f;
    float bf0 = 0.f, bf1 = 0.f;
    if (MODE == 1) {
        wf00 = Wf[(col) * 2 + 0];      wf10 = Wf[(col) * 2 + 1];
        wf01 = Wf[(16 + col) * 2 + 0]; wf11 = Wf[(16 + col) * 2 + 1];
        wf02 = Wf[(32 + col) * 2 + 0]; wf12 = Wf[(32 + col) * 2 + 1];
        bf0 = bfin[0]; bf1 = bfin[1];
    }
    float s0 = 0.f, s1 = 0.f, s2 = 0.f, q0 = 0.f, q1 = 0.f, q2 = 0.f;

    const int ntiles = (nN + 15) >> 4;
    for (int tile = blockIdx.x * 4 + wid; tile < ntiles; tile += gridDim.x * 4) {
        int n0 = tile << 4;
        int arow = n0 + col;
        bool rowok = arow < nN;
        f32x4 acc0 = {0.f, 0.f, 0.f, 0.f};
        f32x4 acc1 = {0.f, 0.f, 0.f, 0.f};
        f32x4 acc2 = {0.f, 0.f, 0.f, 0.f};
#pragma unroll
        for (int c = 0; c < NC; ++c) {
            int k = c * 32 + sub * 8;
            short8 a = {};
            if (rowok && k < K) {
                int t = k / WIN, f = k % WIN;
                a = *(const short8*)(Tslab + (size_t)t * termStride + (size_t)arow * WIN + f);
            }
            acc0 = __builtin_amdgcn_mfma_f32_16x16x32_bf16(a, bfrag[0][c], acc0, 0, 0, 0);
            acc1 = __builtin_amdgcn_mfma_f32_16x16x32_bf16(a, bfrag[1][c], acc1, 0, 0, 0);
            acc2 = __builtin_amdgcn_mfma_f32_16x16x32_bf16(a, bfrag[2][c], acc2, 0, 0, 0);
        }
        int nb = n0 + sub * 4;
        if (MODE == 0) {
#pragma unroll
            for (int r = 0; r < 4; ++r) {
                int n = nb + r;
                if (n < nN) {
                    float v0 = acc0[r] + bj0;
                    float v1 = acc1[r] + bj1;
                    float v2 = acc2[r] + bj2;
                    size_t ro = (size_t)n * NHID;
                    Hout[ro + col]      = (unsigned short)bf_rne(v0);
                    Hout[ro + 16 + col] = (unsigned short)bf_rne(v1);
                    Hout[ro + 32 + col] = (unsigned short)bf_rne(v2);
                    s0 += v0; q0 += v0 * v0;
                    s1 += v1; q1 += v1 * v1;
                    s2 += v2; q2 += v2 * v2;
                }
            }
        } else {
#pragma unroll
            for (int r = 0; r < 4; ++r) {
                float p0 = fmaf(acc0[r] + bj0, wf00, fmaf(acc1[r] + bj1, wf01, (acc2[r] + bj2) * wf02));
                float p1 = fmaf(acc0[r] + bj0, wf10, fmaf(acc1[r] + bj1, wf11, (acc2[r] + bj2) * wf12));
                p0 += __shfl_xor(p0, 1); p0 += __shfl_xor(p0, 2);
                p0 += __shfl_xor(p0, 4); p0 += __shfl_xor(p0, 8);
                p1 += __shfl_xor(p1, 1); p1 += __shfl_xor(p1, 2);
                p1 += __shfl_xor(p1, 4); p1 += __shfl_xor(p1, 8);
                int n = nb + r;
                if (col == 0 && n < nN) {
                    out[(size_t)n * 2 + 0] = p0 + bf0;
                    out[(size_t)n * 2 + 1] = p1 + bf1;
                }
            }
        }
    }
    if (MODE == 0) {
        s0 += __shfl_xor(s0, 16); s0 += __shfl_xor(s0, 32);
        s1 += __shfl_xor(s1, 16); s1 += __shfl_xor(s1, 32);
        s2 += __shfl_xor(s2, 16); s2 += __shfl_xor(s2, 32);
        q0 += __shfl_xor(q0, 16); q0 += __shfl_xor(q0, 32);
        q1 += __shfl_xor(q1, 16); q1 += __shfl_xor(q1, 32);
        q2 += __shfl_xor(q2, 16); q2 += __shfl_xor(q2, 32);
        __shared__ float red[4][96];
        if (lane < 16) {
            red[wid][col]      = s0; red[wid][16 + col] = s1; red[wid][32 + col] = s2;
            red[wid][48 + col] = q0; red[wid][64 + col] = q1; red[wid][80 + col] = q2;
        }
        __syncthreads();
        int t = threadIdx.x;
        if (t < 96) atomicAdd(&bns[t], red[0][t] + red[1][t] + red[2][t] + red[3][t]);
    }
}

// ---------- batchnorm apply + LeakyReLU (grid-stride) ----------
__global__ void k_bn_apply(const unsigned short* __restrict__ Hin, unsigned short* __restrict__ T0,
                           const float* __restrict__ sums, const float* __restrict__ g,
                           const float* __restrict__ b, int nN) {
    int col = threadIdx.x;
    float inv = 1.f / (float)nN;
    float mu = sums[col] * inv;
    float var = sums[NHID + col] * inv - mu * mu;
    float rs = rsqrtf(var + BN_EPS) * g[col];
    float bb = b[col];
    for (int n = blockIdx.x * 8 + threadIdx.y; n < nN; n += gridDim.x * 8) {
        size_t o = (size_t)n * NHID + col;
        float y = (bf_lo(Hin[o]) - mu) * rs + bb;
        y = (y >= 0.f) ? y : SLOPE * y;
        T0[o] = (unsigned short)bf_rne(y);
    }
}

extern "C" void kernel_launch(void* const* d_in, const int* in_sizes, int n_in,
                              void* d_out, int out_size, void* d_ws, size_t ws_size,
                              hipStream_t stream) {
    const float* x   = (const float*)d_in[0];
    const int*   ei  = (const int*)d_in[1];
    const float* W1  = (const float*)d_in[2];
    const float* b1  = (const float*)d_in[3];
    const float* W2  = (const float*)d_in[4];
    const float* b2  = (const float*)d_in[5];
    const float* W3  = (const float*)d_in[6];
    const float* b3  = (const float*)d_in[7];
    const float* g1  = (const float*)d_in[8];
    const float* bt1 = (const float*)d_in[9];
    const float* g2  = (const float*)d_in[10];
    const float* bt2 = (const float*)d_in[11];
    const float* Wf  = (const float*)d_in[12];
    const float* bf  = (const float*)d_in[13];
    float* out = (float*)d_out;

    const int nN = in_sizes[0] / 64;
    const int nE = in_sizes[1] / 2;
    const int* src = ei;
    const int* dst = ei + nE;

    size_t off = 0;
    auto carve = [&](size_t bytes) -> void* {
        void* p = (char*)d_ws + off;
        off += (bytes + 255) & ~(size_t)255;
        return p;
    };
    float*          dinv = (float*)carve((size_t)nN * 4);
    int*            cur  = (int*)carve((size_t)nN * 4);
    int*            csrc = (int*)carve((size_t)nN * DMAX * 4);
    unsigned short* slab = (unsigned short*)carve((size_t)nN * 64 * 2 * 5);  // [5][nN][64]; 48-slab aliases
    unsigned short* H    = (unsigned short*)carve((size_t)nN * NHID * 2);
    float*          bns  = (float*)carve(2 * NHID * 4);

    const size_t ts64 = (size_t)nN * 64;
    const size_t ts48 = (size_t)nN * NHID;

    // dinv and cur are adjacent carves (256-aligned) -> one memset covers both
    hipMemsetAsync(dinv, 0, (size_t)((char*)csrc - (char*)dinv), stream);

    k_setup<<<4096, 256, 0, stream>>>(src, dst, dinv, cur, csrc, nE);
    k_dinvcast<<<2048, 256, 0, stream>>>(dinv, nN, (const float4*)x, (uint2*)slab, nN * 16);

    const int gP = 2048;             // 8192 resident waves: 2048 blocks x 4 waves (R10 best)
    const dim3 blkP(64, 4);
    const int gM = 512;

    auto prop = [&](const unsigned short* Tin, const unsigned short* Tprev,
                    unsigned short* Tout, int NVw, int mode) {
        if (NVw == 8)
            k_prop<8><<<gP, blkP, 0, stream>>>((const uint4*)Tin, (const uint4*)(Tprev ? Tprev : Tin),
                                               (uint4*)Tout, cur, csrc, dinv, nN, mode);
        else
            k_prop<6><<<gP, blkP, 0, stream>>>((const uint4*)Tin, (const uint4*)(Tprev ? Tprev : Tin),
                                               (uint4*)Tout, cur, csrc, dinv, nN, mode);
    };

    // ---- layer 1 (Win=64) ----
    unsigned short* L1[5];
    for (int t = 0; t < 5; ++t) L1[t] = slab + t * ts64;
    prop(L1[0], nullptr, L1[1], 8, 0);
    prop(L1[1], L1[0], L1[2], 8, 1);
    prop(L1[2], L1[1], L1[3], 8, 1);
    prop(L1[3], L1[2], L1[4], 8, 1);
    hipMemsetAsync(bns, 0, 2 * NHID * 4, stream);
    k_mmf<64, 0><<<gM, 256, 0, stream>>>(slab, W1, b1, H, bns, nullptr, nullptr, nullptr, nN);
    k_bn_apply<<<1024, dim3(NHID, 8), 0, stream>>>(H, slab, bns, g1, bt1, nN);

    // ---- layer 2 (Win=48) ----
    unsigned short* L2[5];
    for (int t = 0; t < 5; ++t) L2[t] = slab + t * ts48;
    prop(L2[0], nullptr, L2[1], 6, 0);
    prop(L2[1], L2[0], L2[2], 6, 1);
    prop(L2[2], L2[1], L2[3], 6, 1);
    prop(L2[3], L2[2], L2[4], 6, 1);
    hipMemsetAsync(bns, 0, 2 * NHID * 4, stream);
    k_mmf<48, 0><<<gM, 256, 0, stream>>>(slab, W2, b2, H, bns, nullptr, nullptr, nullptr, nN);
    k_bn_apply<<<1024, dim3(NHID, 8), 0, stream>>>(H, slab, bns, g2, bt2, nN);

    // ---- layer 3 (Win=48) + fused final linear ----
    prop(L2[0], nullptr, L2[1], 6, 0);
    prop(L2[1], L2[0], L2[2], 6, 1);
    prop(L2[2], L2[1], L2[3], 6, 1);
    prop(L2[3], L2[2], L2[4], 6, 1);
    k_mmf<48, 1><<<gM, 256, 0, stream>>>(slab, W3, b3, nullptr, nullptr, Wf, bf, out, nN);
}